// Round 3
// baseline (934.336 us; speedup 1.0000x reference)
//
#include <hip/hip_runtime.h>
#include <hip/hip_bf16.h>
#include <stdint.h>

#define B_ 2
#define N_ 4096
#define D_ 128
#define H_ 4
#define HID_ 32
#define EN_ 16
#define ALPHA_ 0.2f

__device__ __forceinline__ float bf2f(unsigned short u) {
    return __uint_as_float(((unsigned int)u) << 16);
}
// monotonic float->uint key for atomicMax over signed floats
__device__ __forceinline__ unsigned int f2key(float x) {
    unsigned int u = __float_as_uint(x);
    return (u & 0x80000000u) ? ~u : (u | 0x80000000u);
}
__device__ __forceinline__ float key2f(unsigned int k) {
    unsigned int u = (k & 0x80000000u) ? (k ^ 0x80000000u) : ~k;
    return __uint_as_float(u);
}

// dtype-adaptive loads (BF = inputs stored as bf16)
template<bool BF> __device__ __forceinline__ float ld1(const void* p, size_t i) {
    if (BF) return bf2f(((const unsigned short*)p)[i]);
    return ((const float*)p)[i];
}
template<bool BF> __device__ __forceinline__ void ld4(float* d, const void* p, size_t i) {
    if (BF) {
        uint2 u = *(const uint2*)((const unsigned short*)p + i);
        d[0] = bf2f(u.x & 0xffffu); d[1] = bf2f(u.x >> 16);
        d[2] = bf2f(u.y & 0xffffu); d[3] = bf2f(u.y >> 16);
    } else {
        float4 v = *(const float4*)((const float*)p + i);
        d[0] = v.x; d[1] = v.y; d[2] = v.z; d[3] = v.w;
    }
}

// ---------- dtype detector + mkey zeroing.
// adj is binary {0,1}. fp32 words are only 0x00000000 / 0x3F800000.
// bf16 pairs produce 0x00003F80 / 0x3F803F80 whenever an even-index elem is 1.
__global__ __launch_bounds__(256) void detect_kernel(
    const unsigned int* __restrict__ adjw, unsigned int* __restrict__ mk)
{
    __shared__ unsigned int any;
    if (threadIdx.x == 0) any = 0u;
    __syncthreads();
    unsigned int loc = 0;
    for (int i = threadIdx.x; i < 4096; i += 256) {
        unsigned int w = adjw[i];
        loc |= (w == 0x00003F80u || w == 0x3F803F80u) ? 1u : 0u;
    }
    if (loc) atomicOr(&any, 1u);
    __syncthreads();
    if (threadIdx.x < 10) mk[threadIdx.x] = 0u;
    if (threadIdx.x == 0) mk[10] = any;
}

// ---------- layer-1 projection: wh[b][h][i][d] = fea[b][i][:] @ W_heads[h][:][d]
template<bool BF> __device__ __forceinline__ void proj1_body(
    const void* fea, const void* Wh, float* __restrict__ wh,
    float* Ws, float (*xs)[D_])
{
    const int b = blockIdx.z, h = blockIdx.y, i0 = blockIdx.x * 8, tid = threadIdx.x;
    const size_t Wo = (size_t)h * D_ * HID_;
    for (int idx = tid * 4; idx < D_ * HID_; idx += 1024) ld4<BF>(&Ws[idx], Wh, Wo + idx);
    const size_t xo = ((size_t)b * N_ + i0) * D_;
    ld4<BF>(&xs[(tid * 4) >> 7][(tid * 4) & 127], fea, xo + tid * 4);
    __syncthreads();
    const int r = tid >> 5, d = tid & 31;
    float acc = 0.f;
#pragma unroll 8
    for (int k = 0; k < D_; ++k) acc += xs[r][k] * Ws[k * HID_ + d];
    wh[(((size_t)b * H_ + h) * N_ + i0 + r) * HID_ + d] = acc;
}
__global__ __launch_bounds__(256) void proj1_kernel(
    const void* fea, const void* Wh, float* wh, const unsigned int* flag)
{
    __shared__ float Ws[D_ * HID_];
    __shared__ float xs[8][D_];
    if (flag[0]) proj1_body<true>(fea, Wh, wh, Ws, xs);
    else         proj1_body<false>(fea, Wh, wh, Ws, xs);
}

// ---------- layer-1: wh1, wh2, per-(b,h) max(wh2)
__global__ __launch_bounds__(128) void proj1b_kernel(
    const float* __restrict__ wh, const void* a_heads,
    float* __restrict__ wh1, float* __restrict__ wh2,
    unsigned int* __restrict__ mkey, const unsigned int* flag)
{
    __shared__ float as_[2 * HID_];
    const int b = blockIdx.z, h = blockIdx.y;
    const int i = blockIdx.x * 128 + threadIdx.x;
    if (threadIdx.x < 2 * HID_)
        as_[threadIdx.x] = flag[0] ? ld1<true>(a_heads, h * 2 * HID_ + threadIdx.x)
                                   : ld1<false>(a_heads, h * 2 * HID_ + threadIdx.x);
    __syncthreads();
    const float* row = wh + (((size_t)b * H_ + h) * N_ + i) * HID_;
    float a1 = 0.f, a2 = 0.f;
#pragma unroll
    for (int d = 0; d < HID_; ++d) { float v = row[d]; a1 += v * as_[d]; a2 += v * as_[HID_ + d]; }
    const size_t o = (size_t)(b * H_ + h) * N_ + i;
    wh1[o] = a1; wh2[o] = a2;
    float m = a2;
#pragma unroll
    for (int off = 32; off; off >>= 1) m = fmaxf(m, __shfl_xor(m, off));
    if ((threadIdx.x & 63) == 0) atomicMax(&mkey[b * H_ + h], f2key(m));
}

// ---------- layer-1 fused attention: x2[b][i][h*32+d] = elu(softmax_row @ wh)
template<bool BF> __device__ void attn1_body(
    const void* adj, const float* __restrict__ wh,
    const float* __restrict__ wh1, const float* __restrict__ wh2,
    const unsigned int* __restrict__ mkey, float* __restrict__ x2,
    float (*adj_s)[16][64], float (*p_s)[16][68],
    float (*wh1_s)[16], float (*m_s)[16], float (*lred)[16])
{
    const int b = blockIdx.y, i0 = blockIdx.x * 16;
    const int tid = threadIdx.x, lane = tid & 63, h = tid >> 6;
    if (lane < 16) {
        float w1 = wh1[(size_t)(b * H_ + h) * N_ + i0 + lane];
        wh1_s[h][lane] = w1;
        float Mh = key2f(mkey[b * H_ + h]);
        float s = w1 + Mh;                 // upper bound on score (lrelu monotone)
        m_s[h][lane] = s > 0.f ? s : ALPHA_ * s;
    }
    float acc[8] = {0, 0, 0, 0, 0, 0, 0, 0};
    float lpart[16];
#pragma unroll
    for (int r = 0; r < 16; ++r) lpart[r] = 0.f;
    const int rv = lane & 15, dq = lane >> 4;        // V-phase mapping: row, d-quarter
    const float* whh = wh + (size_t)(b * H_ + h) * N_ * HID_;
    const float* wh2h = wh2 + (size_t)(b * H_ + h) * N_;
    const size_t adjo = ((size_t)b * N_ + i0) * N_;
    const int sr = tid >> 4, sc4 = (tid & 15) * 4;   // adj staging map (4 elems/lane)
    __syncthreads();
    for (int jt = 0, buf = 0; jt < N_; jt += 64, buf ^= 1) {
        ld4<BF>(&adj_s[buf][sr][sc4], adj, adjo + (size_t)sr * N_ + jt + sc4);
        __syncthreads();
        // Phase P: lane <-> column j
        float w2v = wh2h[jt + lane];
#pragma unroll
        for (int r = 0; r < 16; ++r) {
            float av = adj_s[buf][r][lane];
            float s = wh1_s[h][r] + w2v;
            float e = s > 0.f ? s : ALPHA_ * s;
            float sc = e * av;
            float p = (av != 0.f && sc != 0.f) ? __expf(sc - m_s[h][r]) : 0.f;
            p_s[h][r][lane] = p;
            lpart[r] += p;
        }
        // p_s is wave-private (per head); ensure our writes landed before reads
        asm volatile("s_waitcnt lgkmcnt(0)" ::: "memory");
        // Phase V: lane <-> (row rv, d-quarter dq)
        const float* vb = whh + (size_t)jt * HID_ + dq * 8;
#pragma unroll 4
        for (int jj = 0; jj < 64; ++jj) {
            float pv = p_s[h][rv][jj];
            const float4* vp = (const float4*)(vb + jj * HID_);
            float4 v0 = vp[0], v1 = vp[1];
            acc[0] += pv * v0.x; acc[1] += pv * v0.y; acc[2] += pv * v0.z; acc[3] += pv * v0.w;
            acc[4] += pv * v1.x; acc[5] += pv * v1.y; acc[6] += pv * v1.z; acc[7] += pv * v1.w;
        }
    }
#pragma unroll
    for (int r = 0; r < 16; ++r) {
        float v = lpart[r];
#pragma unroll
        for (int off = 32; off; off >>= 1) v += __shfl_xor(v, off);
        if (lane == 0) lred[h][r] = v;
    }
    __syncthreads();
    float linv = 1.f / fmaxf(lred[h][rv], 1e-30f);
    float* orow = x2 + ((size_t)b * N_ + i0 + rv) * (H_ * HID_) + h * HID_ + dq * 8;
#pragma unroll
    for (int k = 0; k < 8; ++k) {
        float v = acc[k] * linv;
        orow[k] = v > 0.f ? v : expm1f(v);   // ELU (concat=True heads)
    }
}
__global__ __launch_bounds__(256) void attn1_kernel(
    const void* adj, const float* wh, const float* wh1, const float* wh2,
    const unsigned int* mkey, float* x2, const unsigned int* flag)
{
    __shared__ float adj_s[2][16][64];
    __shared__ float p_s[H_][16][68];
    __shared__ float wh1_s[H_][16], m_s[H_][16], lred[H_][16];
    if (flag[0]) attn1_body<true>(adj, wh, wh1, wh2, mkey, x2, adj_s, p_s, wh1_s, m_s, lred);
    else         attn1_body<false>(adj, wh, wh1, wh2, mkey, x2, adj_s, p_s, wh1_s, m_s, lred);
}

// ---------- layer-2 projection: whl2 = x2 @ W_last
template<bool BF> __device__ __forceinline__ void proj2_body(
    const float* __restrict__ x2, const void* Wl, float* __restrict__ whl2,
    float* Ws, float (*xs)[D_])
{
    const int b = blockIdx.y, i0 = blockIdx.x * 16, tid = threadIdx.x;
    for (int idx = tid * 4; idx < D_ * EN_; idx += 1024) ld4<BF>(&Ws[idx], Wl, idx);
    const float* xp = x2 + ((size_t)b * N_ + i0) * D_;
    for (int idx = tid * 4; idx < 16 * D_; idx += 1024)
        *(float4*)&xs[idx >> 7][idx & 127] = *(const float4*)(xp + idx);
    __syncthreads();
    const int r = tid >> 4, e = tid & 15;
    float acc = 0.f;
#pragma unroll 8
    for (int k = 0; k < D_; ++k) acc += xs[r][k] * Ws[k * EN_ + e];
    whl2[((size_t)b * N_ + i0 + r) * EN_ + e] = acc;
}
__global__ __launch_bounds__(256) void proj2_kernel(
    const float* x2, const void* Wl, float* whl2, const unsigned int* flag)
{
    __shared__ float Ws[D_ * EN_];
    __shared__ float xs[16][D_];
    if (flag[0]) proj2_body<true>(x2, Wl, whl2, Ws, xs);
    else         proj2_body<false>(x2, Wl, whl2, Ws, xs);
}

// ---------- layer-2: wh1b, wh2b, per-b max
__global__ __launch_bounds__(128) void proj2b_kernel(
    const float* __restrict__ whl2, const void* a_last,
    float* __restrict__ wh1b, float* __restrict__ wh2b,
    unsigned int* __restrict__ mkey2, const unsigned int* flag)
{
    __shared__ float as_[2 * EN_];
    const int b = blockIdx.y;
    const int i = blockIdx.x * 128 + threadIdx.x;
    if (threadIdx.x < 2 * EN_)
        as_[threadIdx.x] = flag[0] ? ld1<true>(a_last, threadIdx.x)
                                   : ld1<false>(a_last, threadIdx.x);
    __syncthreads();
    const float* row = whl2 + ((size_t)b * N_ + i) * EN_;
    float a1 = 0.f, a2 = 0.f;
#pragma unroll
    for (int e = 0; e < EN_; ++e) { float v = row[e]; a1 += v * as_[e]; a2 += v * as_[EN_ + e]; }
    wh1b[(size_t)b * N_ + i] = a1; wh2b[(size_t)b * N_ + i] = a2;
    float m = a2;
#pragma unroll
    for (int off = 32; off; off >>= 1) m = fmaxf(m, __shfl_xor(m, off));
    if ((threadIdx.x & 63) == 0) atomicMax(mkey2 + b, f2key(m));
}

// ---------- layer-2 fused attention + final ELU, fp32 store
template<bool BF> __device__ void attn2_body(
    const void* adj, const float* __restrict__ whl2,
    const float* __restrict__ wh1b, const float* __restrict__ wh2b,
    const unsigned int* __restrict__ mkey2, float* __restrict__ out,
    float (*adj_s)[32][64], float (*p_s)[69],
    float* wh1_s, float* m_s, float* lred)
{
    const int b = blockIdx.y, i0 = blockIdx.x * 32;
    const int tid = threadIdx.x, lane = tid & 63, w = tid >> 6;
    if (tid < 32) {
        float w1 = wh1b[(size_t)b * N_ + i0 + tid];
        wh1_s[tid] = w1;
        float Mh = key2f(mkey2[b]);
        float s = w1 + Mh;
        m_s[tid] = s > 0.f ? s : ALPHA_ * s;
    }
    float accv = 0.f;
    float lpart[4] = {0, 0, 0, 0};
    const int rv = tid & 31, dg = tid >> 5;      // V-phase: row, e-index (0..15)
    const size_t adjo = ((size_t)b * N_ + i0) * N_;
    const int sr = tid >> 4, sc4 = (tid & 15) * 4;
    __syncthreads();
    for (int jt = 0, buf = 0; jt < N_; jt += 64, buf ^= 1) {
        ld4<BF>(&adj_s[buf][sr][sc4], adj, adjo + (size_t)sr * N_ + jt + sc4);
        __syncthreads();
        float w2v = wh2b[(size_t)b * N_ + jt + lane];
#pragma unroll
        for (int q = 0; q < 4; ++q) {
            int r = w * 4 + q;
            float av = adj_s[buf][r][lane];
            float s = wh1_s[r] + w2v;
            float e = s > 0.f ? s : ALPHA_ * s;
            float sc = e * av;
            float p = (av != 0.f && sc != 0.f) ? __expf(sc - m_s[r]) : 0.f;
            p_s[r][lane] = p;
            lpart[q] += p;
        }
        __syncthreads();                         // p_s is cross-wave in phase V
        const float* vb = whl2 + ((size_t)b * N_ + jt) * EN_ + dg;
#pragma unroll 8
        for (int jj = 0; jj < 64; ++jj) {
            accv += p_s[rv][jj] * vb[jj * EN_];
        }
    }
#pragma unroll
    for (int q = 0; q < 4; ++q) {
        float v = lpart[q];
#pragma unroll
        for (int off = 32; off; off >>= 1) v += __shfl_xor(v, off);
        if (lane == 0) lred[w * 4 + q] = v;
    }
    __syncthreads();
    float linv = 1.f / fmaxf(lred[rv], 1e-30f);
    float v = accv * linv;
    float res = v > 0.f ? v : expm1f(v);         // final ELU
    out[((size_t)b * N_ + i0 + rv) * EN_ + dg] = res;
}
__global__ __launch_bounds__(512) void attn2_kernel(
    const void* adj, const float* whl2, const float* wh1b, const float* wh2b,
    const unsigned int* mkey2, float* out, const unsigned int* flag)
{
    __shared__ float adj_s[2][32][64];
    __shared__ float p_s[32][69];
    __shared__ float wh1_s[32], m_s[32], lred[32];
    if (flag[0]) attn2_body<true>(adj, whl2, wh1b, wh2b, mkey2, out, adj_s, p_s, wh1_s, m_s, lred);
    else         attn2_body<false>(adj, whl2, wh1b, wh2b, mkey2, out, adj_s, p_s, wh1_s, m_s, lred);
}

extern "C" void kernel_launch(void* const* d_in, const int* in_sizes, int n_in,
                              void* d_out, int out_size, void* d_ws, size_t ws_size,
                              hipStream_t stream)
{
    const void* fea = d_in[0];
    const void* adj = d_in[1];
    const void* Wh  = d_in[2];
    const void* ah  = d_in[3];
    const void* Wl  = d_in[4];
    const void* al  = d_in[5];

    float* ws   = (float*)d_ws;
    float* wh   = ws;                                  // B*H*N*HID
    float* wh1  = wh  + (size_t)B_ * H_ * N_ * HID_;   // B*H*N
    float* wh2  = wh1 + (size_t)B_ * H_ * N_;          // B*H*N
    float* x2   = wh2 + (size_t)B_ * H_ * N_;          // B*N*128
    float* whl2 = x2  + (size_t)B_ * N_ * D_;          // B*N*EN
    float* wh1b = whl2 + (size_t)B_ * N_ * EN_;        // B*N
    float* wh2b = wh1b + (size_t)B_ * N_;              // B*N
    unsigned int* mkey = (unsigned int*)(wh2b + (size_t)B_ * N_);  // [0..7] L1, [8..9] L2, [10] flag
    const unsigned int* flag = mkey + 10;

    detect_kernel<<<1, 256, 0, stream>>>((const unsigned int*)adj, mkey);
    proj1_kernel<<<dim3(N_ / 8, H_, B_), 256, 0, stream>>>(fea, Wh, wh, flag);
    proj1b_kernel<<<dim3(N_ / 128, H_, B_), 128, 0, stream>>>(wh, ah, wh1, wh2, mkey, flag);
    attn1_kernel<<<dim3(N_ / 16, B_), 256, 0, stream>>>(adj, wh, wh1, wh2, mkey, x2, flag);
    proj2_kernel<<<dim3(N_ / 16, B_), 256, 0, stream>>>(x2, Wl, whl2, flag);
    proj2b_kernel<<<dim3(N_ / 128, B_), 128, 0, stream>>>(whl2, al, wh1b, wh2b, mkey + 8, flag);
    attn2_kernel<<<dim3(N_ / 32, B_), 512, 0, stream>>>(adj, whl2, wh1b, wh2b, mkey + 8,
                                                        (float*)d_out, flag);
}

// Round 5
// 341.624 us; speedup vs baseline: 2.7350x; 2.7350x over previous
//
#include <hip/hip_runtime.h>
#include <hip/hip_bf16.h>
#include <stdint.h>

#define B_ 2
#define N_ 4096
#define D_ 128
#define H_ 4
#define HID_ 32
#define EN_ 16
#define ALPHA_ 0.2f

typedef __attribute__((ext_vector_type(8))) short bf16x8;
typedef __attribute__((ext_vector_type(4))) float f32x4;
typedef __attribute__((ext_vector_type(8))) unsigned short u16x8;

__device__ __forceinline__ float bf2f(unsigned short u) {
    return __uint_as_float(((unsigned int)u) << 16);
}
__device__ __forceinline__ unsigned short f2bf_rne(float x) {
    unsigned int u = __float_as_uint(x);
    unsigned int r = ((u >> 16) & 1u) + 0x7fffu;
    return (unsigned short)((u + r) >> 16);
}
// monotonic float->uint key for atomicMax over signed floats
__device__ __forceinline__ unsigned int f2key(float x) {
    unsigned int u = __float_as_uint(x);
    return (u & 0x80000000u) ? ~u : (u | 0x80000000u);
}
__device__ __forceinline__ float key2f(unsigned int k) {
    unsigned int u = (k & 0x80000000u) ? (k ^ 0x80000000u) : ~k;
    return __uint_as_float(u);
}

__global__ __launch_bounds__(64) void zero_kernel(unsigned int* mk) {
    if (threadIdx.x < 16) mk[threadIdx.x] = 0u;
}

// ---------- layer-1 projection: wh[b][h][i][d] = fea[b][i][:] @ W_heads[h][:][d]
__global__ __launch_bounds__(256) void proj1_kernel(
    const float* __restrict__ fea, const float* __restrict__ Wh,
    float* __restrict__ wh)
{
    __shared__ float Ws[D_ * HID_];   // 16 KB
    __shared__ float xs[8][D_];       // 4 KB
    const int b = blockIdx.z, h = blockIdx.y;
    const int i0 = blockIdx.x * 8;
    const int tid = threadIdx.x;
    const float* Wp = Wh + h * D_ * HID_;
    for (int idx = tid * 4; idx < D_ * HID_; idx += 1024)
        *(float4*)&Ws[idx] = *(const float4*)(Wp + idx);
    const float* xp = fea + ((size_t)b * N_ + i0) * D_;
    *(float4*)&xs[(tid * 4) >> 7][(tid * 4) & 127] = *(const float4*)(xp + tid * 4);
    __syncthreads();
    const int r = tid >> 5, d = tid & 31;
    float acc = 0.f;
#pragma unroll 8
    for (int k = 0; k < D_; ++k) acc += xs[r][k] * Ws[k * HID_ + d];
    wh[(((size_t)b * H_ + h) * N_ + i0 + r) * HID_ + d] = acc;
}

// ---------- layer-1: wh1, wh2, per-(b,h) max(wh2), + bf16 transpose whTt[b][h][jblk][32][64]
__global__ __launch_bounds__(128) void proj1b_kernel(
    const float* __restrict__ wh, const float* __restrict__ a_heads,
    float* __restrict__ wh1, float* __restrict__ wh2,
    unsigned int* __restrict__ mkey, unsigned short* __restrict__ whTt)
{
    __shared__ float as_[2 * HID_];
    __shared__ unsigned short ts[32][136];   // row = 272 B (16-aligned for b128 reads)
    const int b = blockIdx.z, h = blockIdx.y, tid = threadIdx.x;
    const int i = blockIdx.x * 128 + tid;
    if (tid < 2 * HID_) as_[tid] = a_heads[h * 2 * HID_ + tid];
    __syncthreads();
    const float* row = wh + (((size_t)b * H_ + h) * N_ + i) * HID_;
    float rv[32];
#pragma unroll
    for (int q = 0; q < 8; ++q) *(float4*)&rv[q * 4] = ((const float4*)row)[q];
    float a1 = 0.f, a2 = 0.f;
#pragma unroll
    for (int d = 0; d < HID_; ++d) {
        float v = rv[d];
        a1 += v * as_[d]; a2 += v * as_[HID_ + d];
        ts[d][tid] = f2bf_rne(v);
    }
    const size_t o = (size_t)(b * H_ + h) * N_ + i;
    wh1[o] = a1; wh2[o] = a2;
    float m = a2;
#pragma unroll
    for (int off = 32; off; off >>= 1) m = fmaxf(m, __shfl_xor(m, off));
    if ((tid & 63) == 0) atomicMax(&mkey[b * H_ + h], f2key(m));
    __syncthreads();
    // write whTt: this block covers jblks (blockIdx.x*2, +1)
    const size_t base = ((size_t)(b * H_ + h) * 64 + blockIdx.x * 2) * 2048;
#pragma unroll
    for (int r = 0; r < 4; ++r) {
        int l = r * 128 + tid;               // 0..511
        int jb = l >> 8, d = (l >> 3) & 31, part = l & 7;
        *(u16x8*)(whTt + base + (size_t)jb * 2048 + d * 64 + part * 8) =
            *(const u16x8*)&ts[d][jb * 64 + part * 8];
    }
}

// ---------- layer-1 fused MFMA attention: x2[b][i][h*32+d] = elu(softmax_row @ wh)
// block 256 = 4 waves (one per head), 16 rows/block, j-tiled by 64, dbuf staging.
__global__ __launch_bounds__(256) void attn1_kernel(
    const float* __restrict__ adj, const unsigned short* __restrict__ whT,
    const float* __restrict__ wh1, const float* __restrict__ wh2,
    const unsigned int* __restrict__ mkey, float* __restrict__ x2)
{
    __shared__ float adj_s[2][16][68];             // 8.7 KB
    __shared__ unsigned short whT_s[2][4][32][72]; // 36.9 KB
    __shared__ float wh2_s[2][H_][64];             // per-head! (R4 bug: was shared across heads)
    __shared__ float lred[4][16];
    const int b = blockIdx.y, i0 = blockIdx.x * 16;
    const int tid = threadIdx.x, lane = tid & 63, h = tid >> 6;
    const int m = lane & 15, quad = lane >> 4;
    const float w1r = wh1[(size_t)(b * H_ + h) * N_ + i0 + m];
    const float Mh = key2f(mkey[b * H_ + h]);
    const float sb = w1r + Mh;                      // upper bound (lrelu monotone)
    const float mr = sb > 0.f ? sb : ALPHA_ * sb;
    const float* adjb = adj + ((size_t)b * N_ + i0) * N_;
    const float* wh2h = wh2 + (size_t)(b * H_ + h) * N_;
    const unsigned short* whTh = whT + (size_t)(b * H_ + h) * 64 * 2048;
    f32x4 acc0 = {0.f, 0.f, 0.f, 0.f}, acc1 = {0.f, 0.f, 0.f, 0.f};
    float lsum = 0.f;
    const int sr = tid >> 4, sc4 = (tid & 15) * 4;

    auto stage = [&](int jt, int buf) {
        *(float4*)&adj_s[buf][sr][sc4] = *(const float4*)(adjb + (size_t)sr * N_ + jt + sc4);
        wh2_s[buf][h][lane] = wh2h[jt + lane];     // each wave stages its own head
        const unsigned short* src = whTh + ((size_t)(jt >> 6)) * 2048;
#pragma unroll
        for (int r = 0; r < 4; ++r) {
            int l = r * 64 + lane;               // 0..255 within head chunk
            int d = l >> 3, part = l & 7;
            *(u16x8*)&whT_s[buf][h][d][part * 8] = *(const u16x8*)(src + l * 8);
        }
    };
    auto compute = [&](int buf) {
#pragma unroll
        for (int ks = 0; ks < 2; ++ks) {
            const int ko = ks * 32 + quad * 8;
            float a[8], w[8];
            *(float4*)&a[0] = *(const float4*)&adj_s[buf][m][ko];
            *(float4*)&a[4] = *(const float4*)&adj_s[buf][m][ko + 4];
            *(float4*)&w[0] = *(const float4*)&wh2_s[buf][h][ko];
            *(float4*)&w[4] = *(const float4*)&wh2_s[buf][h][ko + 4];
            bf16x8 af;
#pragma unroll
            for (int jj = 0; jj < 8; ++jj) {
                float s = w1r + w[jj];
                float e = s > 0.f ? s : ALPHA_ * s;
                float sc = e * a[jj];
                float p = (a[jj] != 0.f && sc != 0.f) ? __expf(sc - mr) : 0.f;
                unsigned short pb = f2bf_rne(p);
                af[jj] = (short)pb;
                lsum += bf2f(pb);                // consistent with MFMA numerator
            }
            bf16x8 b0 = *(const bf16x8*)&whT_s[buf][h][m][ko];
            bf16x8 b1 = *(const bf16x8*)&whT_s[buf][h][m + 16][ko];
            acc0 = __builtin_amdgcn_mfma_f32_16x16x32_bf16(af, b0, acc0, 0, 0, 0);
            acc1 = __builtin_amdgcn_mfma_f32_16x16x32_bf16(af, b1, acc1, 0, 0, 0);
        }
    };

    stage(0, 0);
    int buf = 0;
    for (int jt = 0; jt < N_; jt += 64) {
        __syncthreads();
        if (jt + 64 < N_) stage(jt + 64, buf ^ 1);
        compute(buf);
        buf ^= 1;
    }
    lsum += __shfl_xor(lsum, 16);
    lsum += __shfl_xor(lsum, 32);
    if (lane < 16) lred[h][lane] = lsum;
    __syncthreads();
    float* obase = x2 + ((size_t)b * N_ + i0) * (H_ * HID_) + h * HID_;
#pragma unroll
    for (int reg = 0; reg < 4; ++reg) {
        int row = quad * 4 + reg;                 // C/D layout: col=lane&15, row=quad*4+reg
        float linv = 1.f / fmaxf(lred[h][row], 1e-30f);
        float v0 = acc0[reg] * linv;
        float v1 = acc1[reg] * linv;
        v0 = v0 > 0.f ? v0 : expm1f(v0);
        v1 = v1 > 0.f ? v1 : expm1f(v1);
        obase[(size_t)row * (H_ * HID_) + m] = v0;
        obase[(size_t)row * (H_ * HID_) + 16 + m] = v1;
    }
}

// ---------- layer-2 projection: whl2 = x2 @ W_last
__global__ __launch_bounds__(256) void proj2_kernel(
    const float* __restrict__ x2, const float* __restrict__ Wl,
    float* __restrict__ whl2)
{
    __shared__ float Ws[D_ * EN_];
    __shared__ float xs[16][D_];
    const int b = blockIdx.y, i0 = blockIdx.x * 16, tid = threadIdx.x;
    for (int idx = tid * 4; idx < D_ * EN_; idx += 1024)
        *(float4*)&Ws[idx] = *(const float4*)(Wl + idx);
    const float* xp = x2 + ((size_t)b * N_ + i0) * D_;
    for (int idx = tid * 4; idx < 16 * D_; idx += 1024)
        *(float4*)&xs[idx >> 7][idx & 127] = *(const float4*)(xp + idx);
    __syncthreads();
    const int r = tid >> 4, e = tid & 15;
    float acc = 0.f;
#pragma unroll 8
    for (int k = 0; k < D_; ++k) acc += xs[r][k] * Ws[k * EN_ + e];
    whl2[((size_t)b * N_ + i0 + r) * EN_ + e] = acc;
}

// ---------- layer-2: wh1b, wh2b, per-b max, + bf16 transpose whT2t[b][jblk][16][64]
__global__ __launch_bounds__(128) void proj2b_kernel(
    const float* __restrict__ whl2, const float* __restrict__ a_last,
    float* __restrict__ wh1b, float* __restrict__ wh2b,
    unsigned int* __restrict__ mkey2, unsigned short* __restrict__ whT2t)
{
    __shared__ float as_[2 * EN_];
    __shared__ unsigned short ts[16][136];   // row = 272 B (16-aligned)
    const int b = blockIdx.y, tid = threadIdx.x;
    const int i = blockIdx.x * 128 + tid;
    if (tid < 2 * EN_) as_[tid] = a_last[tid];
    __syncthreads();
    const float* row = whl2 + ((size_t)b * N_ + i) * EN_;
    float rv[16];
#pragma unroll
    for (int q = 0; q < 4; ++q) *(float4*)&rv[q * 4] = ((const float4*)row)[q];
    float a1 = 0.f, a2 = 0.f;
#pragma unroll
    for (int e = 0; e < EN_; ++e) {
        float v = rv[e];
        a1 += v * as_[e]; a2 += v * as_[EN_ + e];
        ts[e][tid] = f2bf_rne(v);
    }
    wh1b[(size_t)b * N_ + i] = a1; wh2b[(size_t)b * N_ + i] = a2;
    float m = a2;
#pragma unroll
    for (int off = 32; off; off >>= 1) m = fmaxf(m, __shfl_xor(m, off));
    if ((tid & 63) == 0) atomicMax(mkey2 + b, f2key(m));
    __syncthreads();
    const size_t base = ((size_t)b * 64 + blockIdx.x * 2) * 1024;
#pragma unroll
    for (int r = 0; r < 2; ++r) {
        int l = r * 128 + tid;               // 0..255
        int jb = l >> 7, d = (l >> 3) & 15, part = l & 7;
        *(u16x8*)(whT2t + base + (size_t)jb * 1024 + d * 64 + part * 8) =
            *(const u16x8*)&ts[d][jb * 64 + part * 8];
    }
}

// ---------- layer-2 fused MFMA attention + final ELU, fp32 store
// block 256 = 4 waves k-slicing a 256-j tile; 16 rows/block; LDS combine.
__global__ __launch_bounds__(256) void attn2_kernel(
    const float* __restrict__ adj, const unsigned short* __restrict__ whT2,
    const float* __restrict__ wh1b, const float* __restrict__ wh2b,
    const unsigned int* __restrict__ mkey2, float* __restrict__ out)
{
    __shared__ float adj_s[2][16][268];            // 34.3 KB
    __shared__ unsigned short wT_s[2][16][264];    // row = 528 B (16-aligned), 16.9 KB
    __shared__ float w2_s[2][256];
    __shared__ float accred[4][16][17];
    __shared__ float lredp[4][16];
    const int b = blockIdx.y, i0 = blockIdx.x * 16;
    const int tid = threadIdx.x, lane = tid & 63, w = tid >> 6;
    const int m = lane & 15, quad = lane >> 4;
    const float w1r = wh1b[(size_t)b * N_ + i0 + m];
    const float Mh = key2f(mkey2[b]);
    const float sb = w1r + Mh;
    const float mr = sb > 0.f ? sb : ALPHA_ * sb;
    const float* adjb = adj + ((size_t)b * N_ + i0) * N_;
    const float* w2g = wh2b + (size_t)b * N_;
    const unsigned short* wTg = whT2 + (size_t)b * 64 * 1024;
    f32x4 acc = {0.f, 0.f, 0.f, 0.f};
    float lsum = 0.f;
    const int sr = tid >> 4, sc = (tid & 15) * 4;

    auto stage = [&](int jt, int buf) {
#pragma unroll
        for (int r = 0; r < 4; ++r)
            *(float4*)&adj_s[buf][sr][r * 64 + sc] =
                *(const float4*)(adjb + (size_t)sr * N_ + jt + r * 64 + sc);
        w2_s[buf][tid] = w2g[jt + tid];
#pragma unroll
        for (int r = 0; r < 2; ++r) {
            int l = r * 256 + tid;               // 0..511
            int jb = l >> 7, t = l & 127;
            int d = t >> 3, part = t & 7;
            *(u16x8*)&wT_s[buf][d][jb * 64 + part * 8] =
                *(const u16x8*)(wTg + ((size_t)(jt >> 6) + jb) * 1024 + d * 64 + part * 8);
        }
    };
    auto compute = [&](int buf) {
#pragma unroll
        for (int ks = 0; ks < 2; ++ks) {
            const int ko = w * 64 + ks * 32 + quad * 8;
            float a[8], ww[8];
            *(float4*)&a[0] = *(const float4*)&adj_s[buf][m][ko];
            *(float4*)&a[4] = *(const float4*)&adj_s[buf][m][ko + 4];
            *(float4*)&ww[0] = *(const float4*)&w2_s[buf][ko];
            *(float4*)&ww[4] = *(const float4*)&w2_s[buf][ko + 4];
            bf16x8 af;
#pragma unroll
            for (int jj = 0; jj < 8; ++jj) {
                float s = w1r + ww[jj];
                float e = s > 0.f ? s : ALPHA_ * s;
                float sc2 = e * a[jj];
                float p = (a[jj] != 0.f && sc2 != 0.f) ? __expf(sc2 - mr) : 0.f;
                unsigned short pb = f2bf_rne(p);
                af[jj] = (short)pb;
                lsum += bf2f(pb);
            }
            bf16x8 bfr = *(const bf16x8*)&wT_s[buf][m][ko];
            acc = __builtin_amdgcn_mfma_f32_16x16x32_bf16(af, bfr, acc, 0, 0, 0);
        }
    };

    stage(0, 0);
    int buf = 0;
    for (int jt = 0; jt < N_; jt += 256) {
        __syncthreads();
        if (jt + 256 < N_) stage(jt + 256, buf ^ 1);
        compute(buf);
        buf ^= 1;
    }
    lsum += __shfl_xor(lsum, 16);
    lsum += __shfl_xor(lsum, 32);
    if (lane < 16) lredp[w][lane] = lsum;
#pragma unroll
    for (int reg = 0; reg < 4; ++reg)
        accred[w][quad * 4 + reg][m] = acc[reg];
    __syncthreads();
    const int row = tid >> 4, col = tid & 15;
    float s = accred[0][row][col] + accred[1][row][col]
            + accred[2][row][col] + accred[3][row][col];
    float l = lredp[0][row] + lredp[1][row] + lredp[2][row] + lredp[3][row];
    float v = s / fmaxf(l, 1e-30f);
    out[((size_t)b * N_ + i0 + row) * EN_ + col] = v > 0.f ? v : expm1f(v);
}

extern "C" void kernel_launch(void* const* d_in, const int* in_sizes, int n_in,
                              void* d_out, int out_size, void* d_ws, size_t ws_size,
                              hipStream_t stream)
{
    const float* fea = (const float*)d_in[0];
    const float* adj = (const float*)d_in[1];
    const float* Wh  = (const float*)d_in[2];
    const float* ah  = (const float*)d_in[3];
    const float* Wl  = (const float*)d_in[4];
    const float* al  = (const float*)d_in[5];

    float* ws   = (float*)d_ws;
    float* wh   = ws;                                  // B*H*N*HID = 1M f
    float* wh1  = wh  + (size_t)B_ * H_ * N_ * HID_;   // 32K f
    float* wh2  = wh1 + (size_t)B_ * H_ * N_;          // 32K f
    float* x2   = wh2 + (size_t)B_ * H_ * N_;          // 1M f
    float* whl2 = x2  + (size_t)B_ * N_ * D_;          // 128K f
    float* wh1b = whl2 + (size_t)B_ * N_ * EN_;        // 8K f
    float* wh2b = wh1b + (size_t)B_ * N_;              // 8K f
    unsigned int* mkey = (unsigned int*)(wh2b + (size_t)B_ * N_);  // 16 u32
    unsigned short* whTt  = (unsigned short*)(mkey + 16);          // B*H*64*2048 sh = 2 MB
    unsigned short* whT2t = whTt + (size_t)B_ * H_ * 64 * 2048;    // B*64*1024 sh = 256 KB

    zero_kernel<<<1, 64, 0, stream>>>(mkey);
    proj1_kernel<<<dim3(N_ / 8, H_, B_), 256, 0, stream>>>(fea, Wh, wh);
    proj1b_kernel<<<dim3(N_ / 128, H_, B_), 128, 0, stream>>>(wh, ah, wh1, wh2, mkey, whTt);
    attn1_kernel<<<dim3(N_ / 16, B_), 256, 0, stream>>>(adj, whTt, wh1, wh2, mkey, x2);
    proj2_kernel<<<dim3(N_ / 16, B_), 256, 0, stream>>>(x2, Wl, whl2);
    proj2b_kernel<<<dim3(N_ / 128, B_), 128, 0, stream>>>(whl2, al, wh1b, wh2b, mkey + 8, whT2t);
    attn2_kernel<<<dim3(N_ / 16, B_), 256, 0, stream>>>(adj, whT2t, wh1b, wh2b, mkey + 8,
                                                        (float*)d_out);
}